// Round 9
// baseline (64.561 us; speedup 1.0000x reference)
//
#include <hip/hip_runtime.h>
#include <math.h>

// PseudoGroupContrast — fp8-queue-resident, high-occupancy (3 blocks/CU).
//
//   grid = B/256, block = 512 (8 waves), LDS ~52 KB -> 3 blocks/CU, 24 waves.
//   Queue (384x128, zero-pad) staged fp32 -> e4m3 fp8 into LDS once/block,
//   XOR-swizzled 8B granules (phys = (seg*4+ks) ^ (row&15)) -> b64 reads at
//   the 4-cyc wave floor. A = e4m3(2*f_hat) built in registers.
//   MFMA f32_16x16x32_fp8_fp8, A/B k-slices aligned (granule seg*4+ks
//   matches A's k = seg*32+ks*8) — fixes the k-permutation of R5-R8.
//
//   S1 = sum exp(2*dot) (9 pad rows -> subtract 9); S2 = label-block sum.
//   def2 = 2*f_hat.ef_hat (fp32-exact).
//   per = log(exp(def2)+S1-9) - (S2+def2)/126; out = sum(mask*per)/B.

#define D        128
#define NQ       375
#define NQP      384
#define QS       125
#define RPB      256          // rows per block (8 waves x 32)
#define NTILES   24
#define INV126   (1.0f/126.0f)

typedef __attribute__((ext_vector_type(4))) float f32x4;

#if defined(__has_builtin)
#if __has_builtin(__builtin_amdgcn_cvt_pk_fp8_f32)
#define HAVE_CVT_FP8 1
#endif
#endif

#ifndef HAVE_CVT_FP8
// software RNE float -> e4m3fn (fallback only)
static __device__ __forceinline__ unsigned f2e4m3_sw(float x) {
    unsigned u = __float_as_uint(x);
    unsigned s = (u >> 24) & 0x80;
    int e = (int)((u >> 23) & 0xFF);
    unsigned m = u & 0x7FFFFF;
    if (e == 0) return s;                       // flush
    int te = e - 120;                           // e4m3 exponent
    unsigned val;
    if (te >= 1) {
        unsigned keep = m >> 20;
        unsigned rest = m & 0xFFFFF;
        keep += (rest > 0x80000) || (rest == 0x80000 && (keep & 1));
        if (keep == 8) { keep = 0; te += 1; }
        val = (te >= 16) ? 0x7E : ((unsigned)(te << 3) | keep);
    } else {
        unsigned full = m | 0x800000;
        int sh = 21 - te;                       // 20 + (1 - te)
        if (sh > 31) val = 0;
        else {
            unsigned keep = full >> sh;
            unsigned rem = full & ((1u << sh) - 1);
            unsigned half = 1u << (sh - 1);
            keep += (rem > half) || (rem == half && (keep & 1));
            val = keep;
        }
    }
    return s | val;
}
#endif

static __device__ __forceinline__ unsigned pk4(float4 v) {
#ifdef HAVE_CVT_FP8
    int r = __builtin_amdgcn_cvt_pk_fp8_f32(v.x, v.y, 0, false);
    r = __builtin_amdgcn_cvt_pk_fp8_f32(v.z, v.w, r, true);
    return (unsigned)r;
#else
    return f2e4m3_sw(v.x) | (f2e4m3_sw(v.y) << 8)
         | (f2e4m3_sw(v.z) << 16) | (f2e4m3_sw(v.w) << 24);
#endif
}

static __device__ __forceinline__ long pk8(float gs, float4 a, float4 b) {
    float4 sa = make_float4(gs * a.x, gs * a.y, gs * a.z, gs * a.w);
    float4 sb = make_float4(gs * b.x, gs * b.y, gs * b.z, gs * b.w);
    unsigned lo = pk4(sa), hi = pk4(sb);
    return (long)(((unsigned long)hi << 32) | (unsigned long)lo);
}

__global__ __launch_bounds__(512, 6) void pgc_main(
    const float* __restrict__ act,
    const float* __restrict__ ema,
    const float* __restrict__ plab,
    const float* __restrict__ mask,
    const float* __restrict__ queue,
    float* __restrict__ out,
    int B, float invB)
{
    __shared__ unsigned char q_lds[NQP * 128];   // 49152 B, fp8, XOR-swizzled
    __shared__ float s_def2[RPB];
    __shared__ float s_mask[RPB];
    __shared__ int   s_lab[RPB];
    __shared__ float s_red[8];

    const int tid = threadIdx.x;
    const int w   = tid >> 6;      // 0..7
    const int l   = tid & 63;
    const int lr  = l & 15;        // fragment row / C col
    const int seg = l >> 4;        // k-segment / C row group
    const long blockBase = (long)blockIdx.x * RPB;
    const float4* q4 = (const float4*)queue;

    // ---- mask / pseudo-label for row `tid` (tid < 256) ----
    if (tid < RPB) {
        long grow = blockBase + tid;
        bool valid = grow < (long)B;
        long g2 = valid ? grow : (long)B - 1;
        float mk = valid ? mask[g2] : 0.f;
        const float* p = plab + g2 * 3;
        float p0 = p[0], p1 = p[1], p2 = p[2];
        int lb = 0; float bst = p0;
        if (p1 > bst) { bst = p1; lb = 1; }   // first-max tie-break = argmax
        if (p2 > bst) { lb = 2; }
        s_mask[tid] = mk;
        s_lab[tid]  = lb;
    }

    // ---- queue staging helper: one batch of 8 float4 / thread ----
    auto qstage = [&](int b) {
        float4 qv[8];
        #pragma unroll
        for (int i = 0; i < 8; ++i) {
            int fi = b * 4096 + i * 512 + tid;          // coalesced
            qv[i] = q4[fi < NQ * 32 ? fi : 0];
        }
        #pragma unroll
        for (int i = 0; i < 8; ++i) {
            int fi = b * 4096 + i * 512 + tid;
            int row = fi >> 5, d = fi & 31;             // dword-in-row
            float4 v = (row < NQ) ? qv[i] : make_float4(0.f, 0.f, 0.f, 0.f);
            int phys = (d >> 1) ^ (row & 15);           // 8B-granule swizzle
            *(unsigned*)&q_lds[(row << 7) + (phys << 3) + ((d & 1) << 2)] = pk4(v);
        }
    };

    long af[2][4];

    // ---- per-group sample staging: act -> af, ema -> def2 (fp32 exact) ----
    auto sgroup = [&](int g) {
        long grow = blockBase + w * 32 + g * 16 + lr;
        if (grow >= (long)B) grow = (long)B - 1;
        const float4* ap = (const float4*)(act + grow * D) + seg * 8;
        const float4* ep = (const float4*)(ema + grow * D) + seg * 8;
        float4 av[8], ev[8];
        #pragma unroll
        for (int i = 0; i < 8; ++i) av[i] = ap[i];
        #pragma unroll
        for (int i = 0; i < 8; ++i) ev[i] = ep[i];

        float ssa = 0.f, sse = 0.f, dae = 0.f;
        #pragma unroll
        for (int i = 0; i < 8; ++i) {
            ssa += av[i].x*av[i].x + av[i].y*av[i].y + av[i].z*av[i].z + av[i].w*av[i].w;
            sse += ev[i].x*ev[i].x + ev[i].y*ev[i].y + ev[i].z*ev[i].z + ev[i].w*ev[i].w;
            dae += av[i].x*ev[i].x + av[i].y*ev[i].y + av[i].z*ev[i].z + av[i].w*ev[i].w;
        }
        ssa += __shfl_xor(ssa, 16); ssa += __shfl_xor(ssa, 32);
        sse += __shfl_xor(sse, 16); sse += __shfl_xor(sse, 32);
        dae += __shfl_xor(dae, 16); dae += __shfl_xor(dae, 32);

        const float inva = 1.0f / fmaxf(sqrtf(ssa), 1e-12f);
        const float inve = 1.0f / fmaxf(sqrtf(sse), 1e-12f);
        const float gs   = 2.0f * inva;   // fold 1/T + norm into A
        #pragma unroll
        for (int ks = 0; ks < 4; ++ks)
            af[g][ks] = pk8(gs, av[2 * ks], av[2 * ks + 1]);   // k = seg*32+ks*8..
        if (seg == 0)
            s_def2[w * 32 + g * 16 + lr] = 2.0f * dae * inva * inve;
    };

    qstage(0);
    sgroup(0);
    qstage(1);
    sgroup(1);
    qstage(2);

    __syncthreads();   // q_lds + stats ready

    // ---- label-block starts for this lane's C rows ----
    int lo8[2][4];
    #pragma unroll
    for (int g = 0; g < 2; ++g)
        #pragma unroll
        for (int r = 0; r < 4; ++r)
            lo8[g][r] = s_lab[w * 32 + g * 16 + seg * 4 + r] * QS;

    float S1[2][4] = {{0.f,0.f,0.f,0.f},{0.f,0.f,0.f,0.f}};
    float S2[2][4] = {{0.f,0.f,0.f,0.f},{0.f,0.f,0.f,0.f}};

    #pragma unroll 4
    for (int nt = 0; nt < NTILES; ++nt) {
        const int row = nt * 16 + lr;
        const int rb  = row << 7;
        const int rx  = row & 15;
        long b[4];
        #pragma unroll
        for (int ks = 0; ks < 4; ++ks)       // granule seg*4+ks == A's k-slice
            b[ks] = *(const long*)&q_lds[rb + ((((seg << 2) + ks) ^ rx) << 3)];
        const int col = row;
        #pragma unroll
        for (int g = 0; g < 2; ++g) {
            f32x4 acc = {0.f, 0.f, 0.f, 0.f};
            acc = __builtin_amdgcn_mfma_f32_16x16x32_fp8_fp8(af[g][0], b[0], acc, 0, 0, 0);
            acc = __builtin_amdgcn_mfma_f32_16x16x32_fp8_fp8(af[g][1], b[1], acc, 0, 0, 0);
            acc = __builtin_amdgcn_mfma_f32_16x16x32_fp8_fp8(af[g][2], b[2], acc, 0, 0, 0);
            acc = __builtin_amdgcn_mfma_f32_16x16x32_fp8_fp8(af[g][3], b[3], acc, 0, 0, 0);
            #pragma unroll
            for (int r = 0; r < 4; ++r) {
                S1[g][r] += __expf(acc[r]);
                if ((unsigned)(col - lo8[g][r]) < (unsigned)QS)
                    S2[g][r] += acc[r];      // acc = 2*dot already
            }
        }
    }

    // ---- reduce over the 16 column lanes ----
    #pragma unroll
    for (int g = 0; g < 2; ++g)
        #pragma unroll
        for (int r = 0; r < 4; ++r) {
            S1[g][r] += __shfl_xor(S1[g][r], 1);
            S1[g][r] += __shfl_xor(S1[g][r], 2);
            S1[g][r] += __shfl_xor(S1[g][r], 4);
            S1[g][r] += __shfl_xor(S1[g][r], 8);
            S2[g][r] += __shfl_xor(S2[g][r], 1);
            S2[g][r] += __shfl_xor(S2[g][r], 2);
            S2[g][r] += __shfl_xor(S2[g][r], 4);
            S2[g][r] += __shfl_xor(S2[g][r], 8);
        }

    float contrib = 0.f;
    if (lr == 0) {
        #pragma unroll
        for (int g = 0; g < 2; ++g)
            #pragma unroll
            for (int r = 0; r < 4; ++r) {
                const int m = w * 32 + g * 16 + seg * 4 + r;
                const float def2  = s_def2[m];
                const float denom = __expf(def2) + S1[g][r] - 9.0f;  // drop pads
                const float per   = __logf(denom) - (S2[g][r] + def2) * INV126;
                contrib += s_mask[m] * per;
            }
    }
    contrib += __shfl_xor(contrib, 16);
    contrib += __shfl_xor(contrib, 32);
    if (l == 0) s_red[w] = contrib;
    __syncthreads();
    if (w == 0) {
        float v = (l < 8) ? s_red[l] : 0.f;
        v += __shfl_xor(v, 1); v += __shfl_xor(v, 2); v += __shfl_xor(v, 4);
        if (l == 0) atomicAdd(out, v * invB);
    }
}

extern "C" void kernel_launch(void* const* d_in, const int* in_sizes, int n_in,
                              void* d_out, int out_size, void* d_ws, size_t ws_size,
                              hipStream_t stream)
{
    const float* act   = (const float*)d_in[0];
    const float* ema   = (const float*)d_in[1];
    const float* plab  = (const float*)d_in[2];
    const float* mask  = (const float*)d_in[3];
    const float* queue = (const float*)d_in[4];
    float* out = (float*)d_out;

    const int B = in_sizes[0] / D;

    hipMemsetAsync(out, 0, sizeof(float), stream);

    const int grid = (B + RPB - 1) / RPB;   // 512 for B=131072 -> 3 blocks/CU capable
    pgc_main<<<grid, 512, 0, stream>>>(act, ema, plab, mask, queue, out,
                                       B, 1.0f / (float)B);
}

// Round 11
// 59.720 us; speedup vs baseline: 1.0811x; 1.0811x over previous
//
#include <hip/hip_runtime.h>
#include <math.h>

// PseudoGroupContrast — barrier-free streaming design.
//
//   prep:  queue fp32 -> fp8 e4m3 in MFMA-fragment-tiled layout in d_ws
//          (unit u = nt*256 + ks*64 + l holds q[nt*16+(l&15)][(l>>4)*32+ks*8 ..+8])
//   main:  grid B/64, block 256 (4 waves), ~24 waves/CU. No LDS data path,
//          no staging barrier. Per wave (16 rows): act+ema streamed to regs
//          (the only HBM traffic), norms/def2 fp32-exact, A packed fp8 with
//          gs = (2/ln2)*inva folded in -> MFMA acc = (2/ln2)*dot.
//          24-tile loop: 4 coalesced b64 B-loads (L2) + 4 fp8 MFMA + 4 exp2.
//          S1 = sum exp2(acc) (9 zero pad rows -> subtract 9)
//          S2 = label-block sum of acc;  def2 = (2/ln2)*f_hat.ef_hat
//          per = ln2*log2(exp2(def2)+S1-9) - ln2*(S2+def2)/126
//          block partial sums -> d_ws (no atomics)
//   finish: reduce 2048 partials -> out (deterministic).

#define D       128
#define NQ      375
#define QS      125
#define NT      24
#define INV126  (1.0f/126.0f)
#define LN2     0.6931471805599453f
#define INVLN2  1.4426950408889634f
#define QT_BYTES 49152
#define NPART    2048

typedef __attribute__((ext_vector_type(4))) float f32x4;

#if defined(__has_builtin)
#if __has_builtin(__builtin_amdgcn_cvt_pk_fp8_f32)
#define HAVE_CVT_FP8 1
#endif
#endif

#ifndef HAVE_CVT_FP8
static __device__ __forceinline__ unsigned f2e4m3_sw(float x) {
    unsigned u = __float_as_uint(x);
    unsigned s = (u >> 24) & 0x80;
    int e = (int)((u >> 23) & 0xFF);
    unsigned m = u & 0x7FFFFF;
    if (e == 0) return s;
    int te = e - 120;
    unsigned val;
    if (te >= 1) {
        unsigned keep = m >> 20;
        unsigned rest = m & 0xFFFFF;
        keep += (rest > 0x80000) || (rest == 0x80000 && (keep & 1));
        if (keep == 8) { keep = 0; te += 1; }
        val = (te >= 16) ? 0x7E : ((unsigned)(te << 3) | keep);
    } else {
        unsigned full = m | 0x800000;
        int sh = 21 - te;
        if (sh > 31) val = 0;
        else {
            unsigned keep = full >> sh;
            unsigned rem = full & ((1u << sh) - 1);
            unsigned half = 1u << (sh - 1);
            keep += (rem > half) || (rem == half && (keep & 1));
            val = keep;
        }
    }
    return s | val;
}
#endif

static __device__ __forceinline__ unsigned pk4(float4 v) {
#ifdef HAVE_CVT_FP8
    int r = __builtin_amdgcn_cvt_pk_fp8_f32(v.x, v.y, 0, false);
    r = __builtin_amdgcn_cvt_pk_fp8_f32(v.z, v.w, r, true);
    return (unsigned)r;
#else
    return f2e4m3_sw(v.x) | (f2e4m3_sw(v.y) << 8)
         | (f2e4m3_sw(v.z) << 16) | (f2e4m3_sw(v.w) << 24);
#endif
}

static __device__ __forceinline__ long pk8(float gs, float4 a, float4 b) {
    float4 sa = make_float4(gs * a.x, gs * a.y, gs * a.z, gs * a.w);
    float4 sb = make_float4(gs * b.x, gs * b.y, gs * b.z, gs * b.w);
    unsigned lo = pk4(sa), hi = pk4(sb);
    return (long)(((unsigned long)hi << 32) | (unsigned long)lo);
}

// ---- prep: queue -> fp8, fragment-tiled ----
__global__ void pgc_prep(const float* __restrict__ queue,
                         unsigned long long* __restrict__ qt)
{
    int u = blockIdx.x * 256 + threadIdx.x;      // 0..6143
    if (u >= 6144) return;
    int l = u & 63, ks = (u >> 6) & 3, nt = u >> 8;
    int row = nt * 16 + (l & 15);
    int k0 = (l >> 4) * 32 + ks * 8;
    float4 a = make_float4(0.f, 0.f, 0.f, 0.f);
    float4 b = make_float4(0.f, 0.f, 0.f, 0.f);
    if (row < NQ) {
        const float* p = queue + row * D + k0;
        a = *(const float4*)p;
        b = *(const float4*)(p + 4);
    }
    unsigned lo = pk4(a), hi = pk4(b);
    qt[u] = ((unsigned long long)hi << 32) | (unsigned long long)lo;
}

// ---- main ----
__global__ __launch_bounds__(256, 6) void pgc_main(
    const float* __restrict__ act,
    const float* __restrict__ ema,
    const float* __restrict__ plab,
    const float* __restrict__ mask,
    const unsigned long long* __restrict__ qt,
    float* __restrict__ partial,
    int B)
{
    __shared__ float s_red[4];

    const int tid = threadIdx.x;
    const int w   = tid >> 6;
    const int l   = tid & 63;
    const int lr  = l & 15;        // own sample row / C col
    const int seg = l >> 4;        // k-segment / C row group

    long grow = (long)blockIdx.x * 64 + w * 16 + lr;
    const bool valid = grow < (long)B;
    const long gr = valid ? grow : (long)B - 1;

    // ---- own-row scalars (duplicated across the 4 seg lanes) ----
    float mk = valid ? mask[gr] : 0.f;
    const float* pp = plab + gr * 3;
    float p0 = pp[0], p1 = pp[1], p2 = pp[2];
    int lb = 0; float bst = p0;
    if (p1 > bst) { bst = p1; lb = 1; }    // first-max tie-break = argmax
    if (p2 > bst) { lb = 2; }
    const int lo_own = lb * QS;

    // ---- act + ema streamed to registers (independent batches) ----
    const float4* ap = (const float4*)(act + gr * D) + seg * 8;
    const float4* ep = (const float4*)(ema + gr * D) + seg * 8;
    float4 av[8], ev[8];
    #pragma unroll
    for (int i = 0; i < 8; ++i) av[i] = ap[i];
    #pragma unroll
    for (int i = 0; i < 8; ++i) ev[i] = ep[i];

    float ssa = 0.f, sse = 0.f, dae = 0.f;
    #pragma unroll
    for (int i = 0; i < 8; ++i) {
        ssa += av[i].x*av[i].x + av[i].y*av[i].y + av[i].z*av[i].z + av[i].w*av[i].w;
        sse += ev[i].x*ev[i].x + ev[i].y*ev[i].y + ev[i].z*ev[i].z + ev[i].w*ev[i].w;
        dae += av[i].x*ev[i].x + av[i].y*ev[i].y + av[i].z*ev[i].z + av[i].w*ev[i].w;
    }
    ssa += __shfl_xor(ssa, 16); ssa += __shfl_xor(ssa, 32);
    sse += __shfl_xor(sse, 16); sse += __shfl_xor(sse, 32);
    dae += __shfl_xor(dae, 16); dae += __shfl_xor(dae, 32);

    const float inva = 1.0f / fmaxf(sqrtf(ssa), 1e-12f);
    const float inve = 1.0f / fmaxf(sqrtf(sse), 1e-12f);
    const float def2 = 2.0f * INVLN2 * dae * inva * inve;   // base-2 domain
    const float gs   = 2.0f * INVLN2 * inva;                // fold 2/ln2 + norm

    long af[4];
    #pragma unroll
    for (int ks = 0; ks < 4; ++ks)                          // k = seg*32+ks*8..
        af[ks] = pk8(gs, av[2 * ks], av[2 * ks + 1]);

    // ---- per-output-row label starts (C row m = seg*4+r lives in lane m) ----
    int lo8[4];
    #pragma unroll
    for (int r = 0; r < 4; ++r) lo8[r] = __shfl(lo_own, seg * 4 + r);

    // ---- 24-tile loop: B from L2-resident tiled fp8 queue ----
    float S1[4] = {0.f, 0.f, 0.f, 0.f};
    float S2[4] = {0.f, 0.f, 0.f, 0.f};

    #pragma unroll 4
    for (int nt = 0; nt < NT; ++nt) {
        long b[4];
        #pragma unroll
        for (int ks = 0; ks < 4; ++ks)
            b[ks] = (long)qt[nt * 256 + ks * 64 + l];       // coalesced b64
        f32x4 acc = {0.f, 0.f, 0.f, 0.f};
        acc = __builtin_amdgcn_mfma_f32_16x16x32_fp8_fp8(af[0], b[0], acc, 0, 0, 0);
        acc = __builtin_amdgcn_mfma_f32_16x16x32_fp8_fp8(af[1], b[1], acc, 0, 0, 0);
        acc = __builtin_amdgcn_mfma_f32_16x16x32_fp8_fp8(af[2], b[2], acc, 0, 0, 0);
        acc = __builtin_amdgcn_mfma_f32_16x16x32_fp8_fp8(af[3], b[3], acc, 0, 0, 0);
        const int col = nt * 16 + lr;
        #pragma unroll
        for (int r = 0; r < 4; ++r) {
            S1[r] += exp2f(acc[r]);
            if ((unsigned)(col - lo8[r]) < (unsigned)QS)
                S2[r] += acc[r];
        }
    }

    // ---- reduce over the 16 column lanes ----
    #pragma unroll
    for (int r = 0; r < 4; ++r) {
        S1[r] += __shfl_xor(S1[r], 1);
        S1[r] += __shfl_xor(S1[r], 2);
        S1[r] += __shfl_xor(S1[r], 4);
        S1[r] += __shfl_xor(S1[r], 8);
        S2[r] += __shfl_xor(S2[r], 1);
        S2[r] += __shfl_xor(S2[r], 2);
        S2[r] += __shfl_xor(S2[r], 4);
        S2[r] += __shfl_xor(S2[r], 8);
    }

    // ---- epilogue: fetch row stats via shuffle (unconditional), then predicate
    float c = 0.f;
    #pragma unroll
    for (int r = 0; r < 4; ++r) {
        const int m = seg * 4 + r;
        const float d2 = __shfl(def2, m);
        const float mm = __shfl(mk, m);
        const float denom = exp2f(d2) + S1[r] - 9.0f;       // drop 9 pad rows
        const float per = LN2 * log2f(denom) - LN2 * (S2[r] + d2) * INV126;
        if (lr == 0) c += mm * per;
    }
    c += __shfl_xor(c, 16);
    c += __shfl_xor(c, 32);
    if (l == 0) s_red[w] = c;
    __syncthreads();
    if (tid == 0)
        partial[blockIdx.x] = s_red[0] + s_red[1] + s_red[2] + s_red[3];
}

// ---- finish: deterministic tree reduce of block partials ----
__global__ void pgc_finish(const float* __restrict__ partial,
                           float* __restrict__ out, int n, float invB)
{
    __shared__ float r[4];
    const int tid = threadIdx.x;
    float s = 0.f;
    for (int i = tid; i < n; i += 256) s += partial[i];
    s += __shfl_xor(s, 1);  s += __shfl_xor(s, 2);
    s += __shfl_xor(s, 4);  s += __shfl_xor(s, 8);
    s += __shfl_xor(s, 16); s += __shfl_xor(s, 32);
    if ((tid & 63) == 0) r[tid >> 6] = s;
    __syncthreads();
    if (tid == 0) out[0] = (r[0] + r[1] + r[2] + r[3]) * invB;
}

extern "C" void kernel_launch(void* const* d_in, const int* in_sizes, int n_in,
                              void* d_out, int out_size, void* d_ws, size_t ws_size,
                              hipStream_t stream)
{
    const float* act   = (const float*)d_in[0];
    const float* ema   = (const float*)d_in[1];
    const float* plab  = (const float*)d_in[2];
    const float* mask  = (const float*)d_in[3];
    const float* queue = (const float*)d_in[4];
    float* out = (float*)d_out;

    const int B = in_sizes[0] / D;

    unsigned long long* qt = (unsigned long long*)d_ws;
    float* partial = (float*)((char*)d_ws + QT_BYTES);

    pgc_prep<<<24, 256, 0, stream>>>(queue, qt);

    const int grid = (B + 63) / 64;          // 2048 for B=131072
    pgc_main<<<grid, 256, 0, stream>>>(act, ema, plab, mask, qt, partial, B);

    pgc_finish<<<1, 256, 0, stream>>>(partial, out, grid, 1.0f / (float)B);
}